// Round 10
// baseline (497.702 us; speedup 1.0000x reference)
//
#include <hip/hip_runtime.h>
#include <math.h>

// Problem constants
#define T_LEN 512
#define B_SZ  32
#define NHEAD 8
#define DHEAD 64
#define H_DIM 512
#define TBTOK 16384          // T*B
#define P_DIM 1152

typedef unsigned short ushort_t;
typedef short short8 __attribute__((ext_vector_type(8)));
typedef float f32x4 __attribute__((ext_vector_type(4)));

__device__ __forceinline__ ushort_t f2bf(float f) {
    union { float f; unsigned int u; } v; v.f = f;
    unsigned int r = v.u + 0x7fffu + ((v.u >> 16) & 1u);
    return (ushort_t)(r >> 16);
}
__device__ __forceinline__ float bf2f(ushort_t h) {
    union { unsigned int u; float f; } v; v.u = ((unsigned int)h) << 16;
    return v.f;
}
__device__ __forceinline__ void gload_lds16(const void* g, void* l) {
    __builtin_amdgcn_global_load_lds(
        (const __attribute__((address_space(1))) void*)g,
        (__attribute__((address_space(3))) void*)l, 16, 0, 0);
}

// ---------------------------------------------------------------------------
// Weight fp32 -> bf16 packing (all 8 matrices into one arena) + accum zero
// ---------------------------------------------------------------------------
__global__ __launch_bounds__(256) void convert_weights(
    const float* __restrict__ wq, const float* __restrict__ wk,
    const float* __restrict__ wv, const float* __restrict__ wo,
    const float* __restrict__ w1, const float* __restrict__ w2,
    const float* __restrict__ l1, const float* __restrict__ l2,
    ushort_t* __restrict__ dst, float* __restrict__ accum)
{
    if (blockIdx.x == 0 && threadIdx.x < 2) accum[threadIdx.x] = 0.f;
    const unsigned int offs[9] = {0u, 327680u, 655360u, 1245184u, 1507328u,
                                  1769472u, 2031616u, 3358720u, 4685824u};
    unsigned int c = (blockIdx.x * 256 + threadIdx.x) * 4;   // element offset
    const float* srcs[8] = {wq, wk, wv, wo, w1, w2, l1, l2};
    int s = 0;
#pragma unroll
    for (int i = 0; i < 7; i++) s += (c >= offs[i + 1]) ? 1 : 0;
    float4 v = *(const float4*)(srcs[s] + (c - offs[s]));
    ushort4 o;
    o.x = f2bf(v.x); o.y = f2bf(v.y); o.z = f2bf(v.z); o.w = f2bf(v.w);
    *(ushort4*)(dst + c) = o;
}

// ---------------------------------------------------------------------------
// Embedding / gather (bf16 outputs) + fused logits tail dot:
// lgits[m] = Ob + dot(pred_bf[m,512:1152], OW[512:])   (values still in regs)
// ---------------------------------------------------------------------------
__global__ __launch_bounds__(256) void embed_kernel(
    const int* __restrict__ ans, const int* __restrict__ cans,
    const int* __restrict__ labels, const float* __restrict__ mask,
    const int* __restrict__ qids, const int* __restrict__ sids,
    const float* __restrict__ smask,
    const float* __restrict__ Eq, const float* __restrict__ Es,
    const float* __restrict__ Ea, const float* __restrict__ El,
    ushort_t* __restrict__ pred_bf, ushort_t* __restrict__ value_bf,
    const float* __restrict__ OW, const float* __restrict__ Ob,
    float* __restrict__ lgits)
{
    __shared__ float red[4];
    int m = blockIdx.x;              // token = t*B + b
    int tid = threadIdx.x;           // 256
    float mval = mask[m];
    int qid = qids[m];
    int a   = ans[m] - 1;
    int ca  = cans[m] - 1;
    int lb  = labels[m];
    ushort_t* pr = pred_bf  + (size_t)m * P_DIM;
    ushort_t* vr = value_bf + (size_t)m * P_DIM;

    float part = 0.f;
    if (tid < 128) {
        ushort_t qv = f2bf(Eq[(size_t)qid * 128 + tid]);
        pr[512 + tid] = qv;
        vr[768 + tid] = qv;
        part = bf2f(qv) * OW[512 + tid];
    }
    int d = tid;                     // 0..255
    float s = 0.f;
#pragma unroll
    for (int j = 0; j < 8; j++) {
        int  sid = sids[m * 8 + j];
        float sm = smask[m * 8 + j];
        s += Es[(size_t)sid * 256 + d] * sm;
    }
    ushort_t sb = f2bf(s);
    pr[640 + d] = sb;
    vr[896 + d] = sb;
    ushort_t cab = f2bf(Ea[ca * 256 + d]);
    pr[896 + d] = cab;
    vr[512 + d] = cab;
    vr[256 + d] = f2bf(Ea[a * 256 + d] * mval);
    vr[0   + d] = f2bf(El[lb * 256 + d] * mval);

    part = fmaf(bf2f(sb),  OW[640 + d], part);
    part = fmaf(bf2f(cab), OW[896 + d], part);
#pragma unroll
    for (int off = 32; off >= 1; off >>= 1) part += __shfl_xor(part, off, 64);
    if ((tid & 63) == 0) red[tid >> 6] = part;
    __syncthreads();
    if (tid == 0) lgits[m] = red[0] + red[1] + red[2] + red[3] + Ob[0];
}

// ---------------------------------------------------------------------------
// MFMA bf16 GEMM: C(M x N) = A(M x K bf16) @ W(N x K bf16)^T + bias
// 128x128 tile, 256 thr (4 waves, 2x2 of 64x64), BK=32, 16x16x32 MFMA.
// Chunk-roll swizzle keeps fragment ds_read_b128 2-way (free).
// Epilogue stage et[4][16][72] UNIONED onto As/Ws (dead after K-loop) ->
// total LDS 16.4 KB for all modes (was 35 KB).
// MODE 1: row-major bf16 store (RELU optional)
// MODE 3: relu, dot with OW, atomicAdd into lg[row] (no store)
// MODE 4: V^T scatter [bh][d][t]; A rows consumed in (b,t)-permuted order
// MODE 5: merged Q|K scatter [bh][t][d]; cols<512 -> Cb (scaled 1/8, bias),
//         cols>=512 -> Cb2 (bias2)
// ---------------------------------------------------------------------------
template<int MODE, bool RELU>
__global__ __launch_bounds__(256) void mgemm(
    const ushort_t* __restrict__ A, int lda,
    const ushort_t* __restrict__ W, int ldw,
    const float* __restrict__ bias, const float* __restrict__ bias2,
    ushort_t* __restrict__ Cb, ushort_t* __restrict__ Cb2, int ldc, int K,
    const float* __restrict__ OW, float* __restrict__ lg)
{
    __shared__ __align__(16) ushort_t smem[128 * 64];   // As | Ws ; et overlay
    ushort_t* As = smem;                 // 128*32
    ushort_t* Ws = smem + 128 * 32;      // 128*32
    ushort_t* et = smem;                 // [4][16][72] after K-loop (4608 el)

    const int m0 = blockIdx.x * 128;
    const int n0 = blockIdx.y * 128;
    const int tid  = threadIdx.x;
    const int wave = tid >> 6;
    const int lane = tid & 63;
    const int wm = wave & 1, wn = wave >> 1;

    f32x4 acc[4][4] = {};

    const int srow = lane >> 2;
    // swizzle: physical LDS chunk = lane&3 (DMA-fixed); global source chunk
    // rolled by (row>>1)&3 so fragment reads spread 2-way across banks.
    const int lchunk = ((((lane & 3) - ((srow >> 1) & 3)) & 3)) * 8;
    int arowA, arowB;
    if (MODE == 4) {
        int mA = m0 + wave * 32 + srow;        // output m = b*512 + t
        int mB = mA + 16;
        arowA = ((mA & 511) << 5) + (mA >> 9); // actual token row t*32+b
        arowB = ((mB & 511) << 5) + (mB >> 9);
    } else {
        arowA = m0 + wave * 32 + srow;
        arowB = arowA + 16;
    }
    const ushort_t* Ag0 = A + (size_t)arowA * lda + lchunk;
    const ushort_t* Ag1 = A + (size_t)arowB * lda + lchunk;
    const ushort_t* Wg0 = W + (size_t)(n0 + wave * 32 + srow) * ldw + lchunk;
    const ushort_t* Wg1 = Wg0 + (size_t)16 * ldw;
    ushort_t* Al0 = &As[(wave * 32) * 32];
    ushort_t* Al1 = &As[(wave * 32 + 16) * 32];
    ushort_t* Wl0 = &Ws[(wave * 32) * 32];
    ushort_t* Wl1 = &Ws[(wave * 32 + 16) * 32];

    const int fr   = lane & 15;      // fragment row(A)/col(B)
    const int quad = lane >> 4;
    // fragment phys chunk: (quad + (row>>1)) & 3; row ≡ fr (mod 8) here
    const int csw  = ((quad + ((fr >> 1) & 3)) & 3) * 8;

    for (int k0 = 0; k0 < K; k0 += 32) {
        gload_lds16(Ag0 + k0, Al0);
        gload_lds16(Ag1 + k0, Al1);
        gload_lds16(Wg0 + k0, Wl0);
        gload_lds16(Wg1 + k0, Wl1);
        __syncthreads();
        short8 af[4], wf[4];
#pragma unroll
        for (int i = 0; i < 4; i++)
            af[i] = *(const short8*)&As[(wm * 64 + i * 16 + fr) * 32 + csw];
#pragma unroll
        for (int j = 0; j < 4; j++)
            wf[j] = *(const short8*)&Ws[(wn * 64 + j * 16 + fr) * 32 + csw];
#pragma unroll
        for (int i = 0; i < 4; i++)
#pragma unroll
            for (int j = 0; j < 4; j++)
                acc[i][j] = __builtin_amdgcn_mfma_f32_16x16x32_bf16(
                    af[i], wf[j], acc[i][j], 0, 0, 0);
        __syncthreads();        // final one also makes As/Ws dead -> et safe
    }

    // C/D layout: col = lane&15, row = quad*4 + reg (per 16x16 frag)
    if (MODE == 3) {
#pragma unroll
        for (int i = 0; i < 4; i++)
#pragma unroll
            for (int r = 0; r < 4; r++) {
                int row = m0 + wm * 64 + i * 16 + quad * 4 + r;
                float part = 0.f;
#pragma unroll
                for (int j = 0; j < 4; j++) {
                    int col = n0 + wn * 64 + j * 16 + fr;
                    float v = fmaxf(acc[i][j][r] + bias[col], 0.f);
                    part = fmaf(v, OW[col], part);
                }
                part += __shfl_xor(part, 1, 64);
                part += __shfl_xor(part, 2, 64);
                part += __shfl_xor(part, 4, 64);
                part += __shfl_xor(part, 8, 64);
                if (fr == 0) atomicAdd(&lg[row], part);
            }
        return;
    }

    const int nbase = n0 + wn * 64;
    bool side = (MODE == 5) && (nbase >= 512);
    const float* bp = side ? bias2 : bias;
    const int boff  = (MODE == 5) ? (nbase & 511) : nbase;
    const float scl = (MODE == 5 && !side) ? 0.125f : 1.f;

    const int sub8 = (lane & 7) * 8;
    const int grp  = lane >> 3;                      // 0..7
    // et accessor: et[(wave*16 + r)*72 + c]

#pragma unroll
    for (int hh = 0; hh < 4; hh++) {
        // ---- stage quarter (wave-private, LDS ops in-order per wave) ----
        if (MODE == 4) {
            // quarter over col-chunks: j = hh -> 16 output d's
#pragma unroll
            for (int i = 0; i < 4; i++)
#pragma unroll
                for (int r = 0; r < 4; r++) {
                    int rl = i * 16 + quad * 4 + r;          // m-local 0..63
                    float v = acc[i][hh][r] + bp[boff + hh * 16 + fr];
                    if (RELU) v = fmaxf(v, 0.f);
                    et[(wave * 16 + fr) * 72 + rl] = f2bf(v);
                }
        } else {
            // quarter over row-chunks: i = hh -> 16 rows
#pragma unroll
            for (int r = 0; r < 4; r++) {
                int rl = quad * 4 + r;                       // 0..15
#pragma unroll
                for (int j = 0; j < 4; j++) {
                    int cl = j * 16 + fr;
                    float v = (acc[hh][j][r] + bp[boff + cl]) * scl;
                    if (RELU) v = fmaxf(v, 0.f);
                    et[(wave * 16 + rl) * 72 + cl] = f2bf(v);
                }
            }
        }
        // ---- coalesced readback + store: 16 rows x 64 cols ----
#pragma unroll
        for (int rr = 0; rr < 2; rr++) {
            int rowl = rr * 8 + grp;                 // 0..15
            short8 val = *(const short8*)&et[(wave * 16 + rowl) * 72 + sub8];
            if (MODE == 1) {
                int row = m0 + wm * 64 + 16 * hh + rowl;
                int col = nbase + sub8;
                *(short8*)&Cb[(size_t)row * ldc + col] = val;
            } else if (MODE == 5) {
                int row = m0 + wm * 64 + 16 * hh + rowl;   // t*32 + b
                int t = row >> 5, b = row & 31;
                int h = (nbase >> 6) & 7;
                ushort_t* base = side ? Cb2 : Cb;
                *(short8*)&base[(((size_t)(b * 8 + h)) << 15) + ((size_t)t << 6) + sub8] = val;
            } else { // MODE 4
                int m = m0 + wm * 64 + sub8;         // 8 consecutive t, same b
                int b = m >> 9, t = m & 511;
                int h = nbase >> 6;
                int d = 16 * hh + rowl;
                *(short8*)&Cb[(((size_t)(b * 8 + h)) << 15) + ((size_t)d << 9) + t] = val;
            }
        }
    }
}

// ---------------------------------------------------------------------------
// MFMA flash attention, no-rescale softmax, cooperative async K/V LDS staging
// (m97-style: prefetch tile i+1 after the loop-top barrier, in flight during
// tile i's compute). XOR-chunk swizzle (phys chunk = (logical+row)&7, applied
// on the per-lane GLOBAL source address) keeps ds_read_b128 bank-uniform.
// grid=(B*NH, 8 rev q-tiles), 256thr. qb pre-scaled 1/8.
// kb: bf16 [bh][t][64]; vtb: bf16 [bh][d][512].
// ---------------------------------------------------------------------------
__global__ __launch_bounds__(256) void attn_mfma(
    const ushort_t* __restrict__ qb, const ushort_t* __restrict__ kb,
    const ushort_t* __restrict__ vtb, const float* __restrict__ mask,
    const float* __restrict__ gammas, ushort_t* __restrict__ attnc)
{
    __shared__ __align__(16) ushort_t kbuf[2][64 * 64];  // 16 KB
    __shared__ __align__(16) ushort_t vbuf[2][64 * 64];  // 16 KB
    __shared__ __align__(16) ushort_t ps[4][16][72];     // P / O stage, per wave
    __shared__ float decayF[512];
    __shared__ float mneg[512];

    const int bh  = blockIdx.x;          // b*8 + h
    const int b   = bh >> 3;
    const int h   = bh & 7;
    const int qt0 = (7 - blockIdx.y) * 64;   // heavy tiles first
    const int tid  = threadIdx.x;
    const int wave = tid >> 6;
    const int lane = tid & 63;
    const int fr   = lane & 15;
    const int quad = lane >> 4;

    {   // LUTs: decay' = clip(exp(-sp*sqrt(d)),1e-5,..)*log2e ; mneg = 0/-1e32
        float g  = gammas[h];
        float sp = (g > 20.f) ? g : log1pf(expf(g));
        for (int i = tid; i < 512; i += 256) {
            decayF[i] = fmaxf(exp2f(-sp * 1.44269504f * sqrtf((float)i)), 1e-5f)
                        * 1.44269504f;
            mneg[i]   = (mask[(size_t)i * B_SZ + b] == 0.f) ? -1e32f : 0.f;
        }
        // visibility covered by the loop-top __syncthreads below
    }

    const int qr0 = qt0 + wave * 16;
    const ushort_t* qbase = qb  + ((size_t)bh << 15);   // [t][64]
    const ushort_t* kbase = kb  + ((size_t)bh << 15);
    const ushort_t* vbase = vtb + ((size_t)bh << 15);   // [d][512]

    short8 af0 = *(const short8*)(qbase + (size_t)(qr0 + fr) * 64 + quad * 8);
    short8 af1 = *(const short8*)(qbase + (size_t)(qr0 + fr) * 64 + 32 + quad * 8);
    const short8 ones = {0x3F80, 0x3F80, 0x3F80, 0x3F80,
                         0x3F80, 0x3F80, 0x3F80, 0x3F80};

    // staging: wave stages local rows [wave*16, wave*16+16) of K and V tiles.
    // lane L covers local row rl = wave*16 + (L>>3), physical chunk L&7;
    // global source chunk = ((L&7) - rl) & 7  (XOR-roll swizzle).
    const int rl0 = wave * 16 + (lane >> 3);
    const int rl1 = rl0 + 8;
    const int sc0 = (((lane & 7) - rl0) & 7) * 8;   // ushort offset
    const int sc1 = (((lane & 7) - rl1) & 7) * 8;

    auto stage = [&](int kt, int bufi) {
        gload_lds16(kbase + (size_t)(kt + rl0) * 64 + sc0, &kbuf[bufi][(wave * 16) * 64]);
        gload_lds16(kbase + (size_t)(kt + rl1) * 64 + sc1, &kbuf[bufi][(wave * 16 + 8) * 64]);
        gload_lds16(vbase + (size_t)rl0 * T_LEN + kt + sc0, &vbuf[bufi][(wave * 16) * 64]);
        gload_lds16(vbase + (size_t)rl1 * T_LEN + kt + sc1, &vbuf[bufi][(wave * 16 + 8) * 64]);
    };
    auto frag = [&](const ushort_t* buf, int row, int lchunk) -> short8 {
        return *(const short8*)&buf[row * 64 + ((lchunk + row) & 7) * 8];
    };

    stage(0, 0);

    f32x4 o[4] = {};                    // O[q=quad*4+r][d=j2*16+fr]
    f32x4 lacc = {};                    // row sums, same layout rows
    int bufi = 0;

    for (int kt0 = 0; kt0 <= qt0; kt0 += 64) {
        __syncthreads();                // drains staged loads; buffer handoff
        if (kt0 < qt0) stage(kt0 + 64, bufi ^ 1);   // prefetch during compute
        const bool diag = (kt0 == qt0);
        const ushort_t* kb_ = kbuf[bufi];
        const ushort_t* vb_ = vbuf[bufi];

        // ---- S = Q K^T (16 x 64) ----
        f32x4 sacc[4] = {};
#pragma unroll
        for (int j = 0; j < 4; j++) {
            int row = j * 16 + fr;
            short8 k0 = frag(kb_, row, quad);
            short8 k1 = frag(kb_, row, quad + 4);
            sacc[j] = __builtin_amdgcn_mfma_f32_16x16x32_bf16(af0, k0, sacc[j], 0, 0, 0);
            sacc[j] = __builtin_amdgcn_mfma_f32_16x16x32_bf16(af1, k1, sacc[j], 0, 0, 0);
        }

        // ---- softmax (no rescale): p = exp2(fma(s, decay', mneg)) ----
#pragma unroll
        for (int j = 0; j < 4; j++) {
            int kg = kt0 + j * 16 + fr;
            float mn = mneg[kg];
            int qgb = qr0 + quad * 4;
            if (!diag) {
                int base = qgb - kg;
#pragma unroll
                for (int r = 0; r < 4; r++) {
                    float t = fmaf(sacc[j][r], decayF[base + r], mn);
                    union { float f; unsigned u; } cv; cv.f = exp2f(t);
                    ps[wave][quad * 4 + r][j * 16 + fr] = (ushort_t)(cv.u >> 16);
                }
            } else {
#pragma unroll
                for (int r = 0; r < 4; r++) {
                    int didx = qgb + r - kg;
                    float dec = decayF[didx > 0 ? didx : 0];
                    float t = fmaf(sacc[j][r], dec, mn);
                    if (didx <= 0) t = -1e32f;      // causal (kg >= qg)
                    union { float f; unsigned u; } cv; cv.f = exp2f(t);
                    ps[wave][quad * 4 + r][j * 16 + fr] = (ushort_t)(cv.u >> 16);
                }
            }
        }
        short8 pf0 = *(const short8*)&ps[wave][fr][quad * 8];
        short8 pf1 = *(const short8*)&ps[wave][fr][32 + quad * 8];
        lacc = __builtin_amdgcn_mfma_f32_16x16x32_bf16(pf0, ones, lacc, 0, 0, 0);
        lacc = __builtin_amdgcn_mfma_f32_16x16x32_bf16(pf1, ones, lacc, 0, 0, 0);
#pragma unroll
        for (int j2 = 0; j2 < 4; j2++) {
            int row = j2 * 16 + fr;
            short8 v0 = frag(vb_, row, quad);
            short8 v1 = frag(vb_, row, quad + 4);
            o[j2] = __builtin_amdgcn_mfma_f32_16x16x32_bf16(pf0, v0, o[j2], 0, 0, 0);
            o[j2] = __builtin_amdgcn_mfma_f32_16x16x32_bf16(pf1, v1, o[j2], 0, 0, 0);
        }
        bufi ^= 1;
    }

    // epilogue: divide by l, zero row q==0, stage + coalesced store
#pragma unroll
    for (int r = 0; r < 4; r++) {
        int qg = qr0 + quad * 4 + r;
        float linv = (qg == 0) ? 0.f : 1.f / lacc[r];
#pragma unroll
        for (int j2 = 0; j2 < 4; j2++)
            ps[wave][quad * 4 + r][j2 * 16 + fr] = f2bf(o[j2][r] * linv);
    }
    const int sub8 = (lane & 7) * 8;
    const int grp  = lane >> 3;
#pragma unroll
    for (int half = 0; half < 2; half++) {
        int rowl = half * 8 + grp;                   // 0..15
        short8 val = *(const short8*)&ps[wave][rowl][sub8];
        int qg = qr0 + rowl;
        *(short8*)&attnc[((size_t)qg * B_SZ + b) * H_DIM + h * DHEAD + sub8] = val;
    }
}

// ---------------------------------------------------------------------------
// LN1: reads bf16 X, writes out1 fp32 + bf16
// ---------------------------------------------------------------------------
__global__ __launch_bounds__(256) void ln1_kernel(
    const ushort_t* __restrict__ X, const float* __restrict__ g,
    const float* __restrict__ bta, float* __restrict__ Y,
    ushort_t* __restrict__ Yb)
{
    int m    = blockIdx.x * 4 + (threadIdx.x >> 6);
    int lane = threadIdx.x & 63;
    int c0   = lane * 8;
    const ushort_t* xr = X + (size_t)m * H_DIM + c0;
    float x[8];
    float s = 0.f, ss = 0.f;
    short8 xv = *(const short8*)xr;
#pragma unroll
    for (int i = 0; i < 8; i++) {
        x[i] = bf2f((ushort_t)xv[i]);
        s += x[i]; ss += x[i] * x[i];
    }
#pragma unroll
    for (int off = 32; off >= 1; off >>= 1) {
        s  += __shfl_xor(s,  off, 64);
        ss += __shfl_xor(ss, off, 64);
    }
    float mu  = s * (1.f / 512.f);
    float var = ss * (1.f / 512.f) - mu * mu;
    float rs  = rsqrtf(var + 1e-5f);
    float  yo[8];
    ushort_t yb[8];
#pragma unroll
    for (int i = 0; i < 8; i++) {
        float v = (x[i] - mu) * rs * g[c0 + i] + bta[c0 + i];
        yo[i] = v; yb[i] = f2bf(v);
    }
    *(float4*)(Y + (size_t)m * H_DIM + c0)     = *(float4*)&yo[0];
    *(float4*)(Y + (size_t)m * H_DIM + c0 + 4) = *(float4*)&yo[4];
    *(short8*)(Yb + (size_t)m * H_DIM + c0)    = *(short8*)&yb[0];
}

// ---------------------------------------------------------------------------
// LN2 + residual + fused OW-dot: pred_bf[:,0:512] = bf16(out1 + LN(f2));
// lgits[m] += dot(fp32 row values, OW[0:512])
// ---------------------------------------------------------------------------
__global__ __launch_bounds__(256) void ln2_kernel(
    const ushort_t* __restrict__ X, const float* __restrict__ g,
    const float* __restrict__ bta, const float* __restrict__ res,
    ushort_t* __restrict__ pred_bf, const float* __restrict__ OW,
    float* __restrict__ lg)
{
    int m    = blockIdx.x * 4 + (threadIdx.x >> 6);
    int lane = threadIdx.x & 63;
    int c0   = lane * 8;
    const ushort_t* xr = X + (size_t)m * H_DIM + c0;
    float x[8];
    float s = 0.f, ss = 0.f;
    short8 xv = *(const short8*)xr;
#pragma unroll
    for (int i = 0; i < 8; i++) {
        x[i] = bf2f((ushort_t)xv[i]);
        s += x[i]; ss += x[i] * x[i];
    }
#pragma unroll
    for (int off = 32; off >= 1; off >>= 1) {
        s  += __shfl_xor(s,  off, 64);
        ss += __shfl_xor(ss, off, 64);
    }
    float mu  = s * (1.f / 512.f);
    float var = ss * (1.f / 512.f) - mu * mu;
    float rs  = rsqrtf(var + 1e-5f);
    float4 r0 = *(const float4*)(res + (size_t)m * H_DIM + c0);
    float4 r1 = *(const float4*)(res + (size_t)m * H_DIM + c0 + 4);
    float rr[8] = {r0.x, r0.y, r0.z, r0.w, r1.x, r1.y, r1.z, r1.w};
    ushort_t yb[8];
    float part = 0.f;
#pragma unroll
    for (int i = 0; i < 8; i++) {
        float v = (x[i] - mu) * rs * g[c0 + i] + bta[c0 + i] + rr[i];
        yb[i] = f2bf(v);
        part = fmaf(v, OW[c0 + i], part);
    }
    *(short8*)(pred_bf + (size_t)m * P_DIM + c0) = *(short8*)&yb[0];
#pragma unroll
    for (int off = 32; off >= 1; off >>= 1) part += __shfl_xor(part, off, 64);
    if (lane == 0) lg[m] += part;
}

// ---------------------------------------------------------------------------
__global__ __launch_bounds__(256) void bce_kernel(
    const float* __restrict__ lg, const int* __restrict__ labels,
    const float* __restrict__ mask, float* __restrict__ accum)
{
    int m    = blockIdx.x * 256 + threadIdx.x;
    int lane = threadIdx.x & 63;
    float l  = lg[m];
    float y  = (float)labels[m];
    float mv = mask[m];
    float a  = (fmaxf(l, 0.f) - l * y + log1pf(expf(-fabsf(l)))) * mv;
#pragma unroll
    for (int off = 32; off >= 1; off >>= 1) {
        a  += __shfl_xor(a,  off, 64);
        mv += __shfl_xor(mv, off, 64);
    }
    if (lane == 0) {
        atomicAdd(accum,     a);
        atomicAdd(accum + 1, mv);
    }
}

__global__ void finalize_kernel(const float* __restrict__ accum, float* __restrict__ out)
{
    out[0] = accum[0] / accum[1];
}

// ---------------------------------------------------------------------------
extern "C" void kernel_launch(void* const* d_in, const int* in_sizes, int n_in,
                              void* d_out, int out_size, void* d_ws, size_t ws_size,
                              hipStream_t stream)
{
    (void)in_sizes; (void)n_in; (void)out_size;
    const int*   ans    = (const int*)  d_in[0];
    const int*   cans   = (const int*)  d_in[1];
    const int*   labels = (const int*)  d_in[2];
    const float* mask   = (const float*)d_in[3];
    const int*   qids   = (const int*)  d_in[4];
    const int*   sids   = (const int*)  d_in[5];
    const float* smask  = (const float*)d_in[6];
    const float* Eq     = (const float*)d_in[7];
    const float* Es     = (const float*)d_in[8];
    const float* Ea     = (const float*)d_in[9];
    const float* El     = (const float*)d_in[10];
    const float* Wq     = (const float*)d_in[11];
    const float* bq     = (const float*)d_in[12];
    const float* Wk     = (const float*)d_in[13];
    const float* bk     = (const float*)d_in[14];
    const float* Wv     = (const float*)d_in[15];
    const float* bv     = (const float*)d_in[16];
    const float* Wo     = (const float*)d_in[17];
    const float* bo     = (const float*)d_in[18];
    const float* ln1_g  = (const float*)d_in[19];
    const float* ln1_b  = (const float*)d_in[20];
    const float* W1     = (const float*)d_in[21];
    const float* b1     = (const float*)d_in[22];
    const float* W2     = (const float*)d_in[23];
    const float* b2     = (const float*)d_in[24];
    const float* ln2_g  = (const float*)d_in[25];
    const float* ln2_b  = (const float*)d_in[26];
    const float* gammas = (const float*)d_in[27];
    const float* L1W    = (const float*)d_in[28];
    const float* L1b    = (const float*)d_in[29];
    const float* L2W    = (const float*)d_in[30];
    const float* L2b    = (const float*)d_in[31];
    const float* OW     = (const float*)d_in[32];
    const float* Ob     = (const float*)d_in[33];
    float* out = (float*)d_out;

    // Arena in units U = TB*64 floats (4 MiB). Peak 42U ≈ 176 MB.
    const size_t U = (size_t)TBTOK * 64;
    if (ws_size < 42 * U * sizeof(float)) return;
    float* ws = (float*)d_ws;
    ushort_t* wtb      = (ushort_t*)(ws);            // [0,3)  weights bf16 (perm)
    ushort_t* pred_bf  = (ushort_t*)(ws + 3 * U);    // [3,12) perm
    ushort_t* value_bf = (ushort_t*)(ws + 12 * U);   // [12,21) until V-gemm
    ushort_t* qb       = (ushort_t*)(ws + 21 * U);   // [21,25) until attn
    ushort_t* kb       = (ushort_t*)(ws + 25 * U);   // [25,29) until attn
    ushort_t* vtb      = (ushort_t*)(ws + 29 * U);   // [29,33) until attn
    ushort_t* attnc_bf = (ushort_t*)(ws + 33 * U);   // [33,37) until Wo
    ushort_t* x1_bf    = (ushort_t*)(ws + 12 * U);   // [12,16) Wo-out / LN1-in
    float*    out1     = ws + 16 * U;                // [16,24) LN1..LN2 fp32
    ushort_t* out1_bf  = (ushort_t*)(ws + 24 * U);   // [24,28)
    ushort_t* f1_bf    = (ushort_t*)(ws + 28 * U);   // [28,32) W1-out
    ushort_t* f2_bf    = (ushort_t*)(ws + 32 * U);   // [32,36) W2-out / LN2-in
    ushort_t* h1_bf    = (ushort_t*)(ws + 12 * U);   // [12,21) L1-out
    float*    lgits    = ws + 41 * U;                // TB floats
    float*    accum    = lgits + TBTOK;

    // bf16 weight arena offsets (elements); wq||wk contiguous for merged QK
    ushort_t* wqk_b = wtb + 0;         // 1024 x 640
    ushort_t* wv_b  = wtb + 655360;
    ushort_t* wo_b  = wtb + 1245184;
    ushort_t* w1_b  = wtb + 1507328;
    ushort_t* w2_b  = wtb + 1769472;
    ushort_t* l1_b  = wtb + 2031616;
    ushort_t* l2_b  = wtb + 3358720;

    convert_weights<<<4576, 256, 0, stream>>>(Wq, Wk, Wv, Wo, W1, W2, L1W, L2W,
                                              wtb, accum);
    // embeddings + fused logits tail dot
    embed_kernel<<<TBTOK, 256, 0, stream>>>(ans, cans, labels, mask, qids, sids,
                                            smask, Eq, Es, Ea, El, pred_bf, value_bf,
                                            OW, Ob, lgits);
    // merged Q|K projection (Q pre-scaled by 1/8), then V^T
    mgemm<5,false><<<dim3(TBTOK/128, 8), 256, 0, stream>>>(
        pred_bf + 512, P_DIM, wqk_b, 640, bq, bk, qb, kb, 0, 640, nullptr, nullptr);
    mgemm<4,false><<<dim3(TBTOK/128, 4), 256, 0, stream>>>(
        value_bf, P_DIM, wv_b, P_DIM, bv, nullptr, vtb, nullptr, 0, P_DIM, nullptr, nullptr);
    // attention (MFMA flash, async LDS staging)
    attn_mfma<<<dim3(B_SZ * NHEAD, 8), 256, 0, stream>>>(
        qb, kb, vtb, mask, gammas, attnc_bf);
    // output projection -> x1_bf
    mgemm<1,false><<<dim3(TBTOK/128, 4), 256, 0, stream>>>(
        attnc_bf, H_DIM, wo_b, H_DIM, bo, nullptr, x1_bf, nullptr, H_DIM, H_DIM, nullptr, nullptr);
    ln1_kernel<<<TBTOK/4, 256, 0, stream>>>(x1_bf, ln1_g, ln1_b, out1, out1_bf);
    // FFN
    mgemm<1,true><<<dim3(TBTOK/128, 4), 256, 0, stream>>>(
        out1_bf, H_DIM, w1_b, H_DIM, b1, nullptr, f1_bf, nullptr, H_DIM, H_DIM, nullptr, nullptr);
    mgemm<1,false><<<dim3(TBTOK/128, 4), 256, 0, stream>>>(
        f1_bf, H_DIM, w2_b, H_DIM, b2, nullptr, f2_bf, nullptr, H_DIM, H_DIM, nullptr, nullptr);
    // LN2 + residual + fused head-dot into lgits
    ln2_kernel<<<TBTOK/4, 256, 0, stream>>>(f2_bf, ln2_g, ln2_b, out1, pred_bf, OW, lgits);
    // L1 (relu)
    mgemm<1,true><<<dim3(TBTOK/128, 9), 256, 0, stream>>>(
        pred_bf, P_DIM, l1_b, P_DIM, L1b, nullptr, h1_bf, nullptr, P_DIM, P_DIM, nullptr, nullptr);
    // L2 (relu) fused with OW dot -> atomics into lgits
    mgemm<3,true><<<dim3(TBTOK/128, 9), 256, 0, stream>>>(
        h1_bf, P_DIM, l2_b, P_DIM, L2b, nullptr, nullptr, nullptr, 0, P_DIM, OW, lgits);
    // BCE + reduction
    bce_kernel<<<TBTOK/256, 256, 0, stream>>>(lgits, labels, mask, accum);
    finalize_kernel<<<1, 1, 0, stream>>>(accum, out);
}

// Round 11
// 472.018 us; speedup vs baseline: 1.0544x; 1.0544x over previous
//
#include <hip/hip_runtime.h>
#include <math.h>

// Problem constants
#define T_LEN 512
#define B_SZ  32
#define NHEAD 8
#define DHEAD 64
#define H_DIM 512
#define TBTOK 16384          // T*B
#define P_DIM 1152

typedef unsigned short ushort_t;
typedef short short8 __attribute__((ext_vector_type(8)));
typedef float f32x4 __attribute__((ext_vector_type(4)));

__device__ __forceinline__ ushort_t f2bf(float f) {
    union { float f; unsigned int u; } v; v.f = f;
    unsigned int r = v.u + 0x7fffu + ((v.u >> 16) & 1u);
    return (ushort_t)(r >> 16);
}
__device__ __forceinline__ float bf2f(ushort_t h) {
    union { unsigned int u; float f; } v; v.u = ((unsigned int)h) << 16;
    return v.f;
}
__device__ __forceinline__ void gload_lds16(const void* g, void* l) {
    __builtin_amdgcn_global_load_lds(
        (const __attribute__((address_space(1))) void*)g,
        (__attribute__((address_space(3))) void*)l, 16, 0, 0);
}

// ---------------------------------------------------------------------------
// Weight fp32 -> bf16 packing (all 8 matrices into one arena) + accum zero
// ---------------------------------------------------------------------------
__global__ __launch_bounds__(256) void convert_weights(
    const float* __restrict__ wq, const float* __restrict__ wk,
    const float* __restrict__ wv, const float* __restrict__ wo,
    const float* __restrict__ w1, const float* __restrict__ w2,
    const float* __restrict__ l1, const float* __restrict__ l2,
    ushort_t* __restrict__ dst, float* __restrict__ accum)
{
    if (blockIdx.x == 0 && threadIdx.x < 2) accum[threadIdx.x] = 0.f;
    const unsigned int offs[9] = {0u, 327680u, 655360u, 1245184u, 1507328u,
                                  1769472u, 2031616u, 3358720u, 4685824u};
    unsigned int c = (blockIdx.x * 256 + threadIdx.x) * 4;   // element offset
    const float* srcs[8] = {wq, wk, wv, wo, w1, w2, l1, l2};
    int s = 0;
#pragma unroll
    for (int i = 0; i < 7; i++) s += (c >= offs[i + 1]) ? 1 : 0;
    float4 v = *(const float4*)(srcs[s] + (c - offs[s]));
    ushort4 o;
    o.x = f2bf(v.x); o.y = f2bf(v.y); o.z = f2bf(v.z); o.w = f2bf(v.w);
    *(ushort4*)(dst + c) = o;
}

// ---------------------------------------------------------------------------
// Embedding / gather (bf16 outputs) + fused logits tail dot:
// lgits[m] = Ob + dot(pred_bf[m,512:1152], OW[512:])   (values still in regs)
// ---------------------------------------------------------------------------
__global__ __launch_bounds__(256) void embed_kernel(
    const int* __restrict__ ans, const int* __restrict__ cans,
    const int* __restrict__ labels, const float* __restrict__ mask,
    const int* __restrict__ qids, const int* __restrict__ sids,
    const float* __restrict__ smask,
    const float* __restrict__ Eq, const float* __restrict__ Es,
    const float* __restrict__ Ea, const float* __restrict__ El,
    ushort_t* __restrict__ pred_bf, ushort_t* __restrict__ value_bf,
    const float* __restrict__ OW, const float* __restrict__ Ob,
    float* __restrict__ lgits)
{
    __shared__ float red[4];
    int m = blockIdx.x;              // token = t*B + b
    int tid = threadIdx.x;           // 256
    float mval = mask[m];
    int qid = qids[m];
    int a   = ans[m] - 1;
    int ca  = cans[m] - 1;
    int lb  = labels[m];
    ushort_t* pr = pred_bf  + (size_t)m * P_DIM;
    ushort_t* vr = value_bf + (size_t)m * P_DIM;

    float part = 0.f;
    if (tid < 128) {
        ushort_t qv = f2bf(Eq[(size_t)qid * 128 + tid]);
        pr[512 + tid] = qv;
        vr[768 + tid] = qv;
        part = bf2f(qv) * OW[512 + tid];
    }
    int d = tid;                     // 0..255
    float s = 0.f;
#pragma unroll
    for (int j = 0; j < 8; j++) {
        int  sid = sids[m * 8 + j];
        float sm = smask[m * 8 + j];
        s += Es[(size_t)sid * 256 + d] * sm;
    }
    ushort_t sb = f2bf(s);
    pr[640 + d] = sb;
    vr[896 + d] = sb;
    ushort_t cab = f2bf(Ea[ca * 256 + d]);
    pr[896 + d] = cab;
    vr[512 + d] = cab;
    vr[256 + d] = f2bf(Ea[a * 256 + d] * mval);
    vr[0   + d] = f2bf(El[lb * 256 + d] * mval);

    part = fmaf(bf2f(sb),  OW[640 + d], part);
    part = fmaf(bf2f(cab), OW[896 + d], part);
#pragma unroll
    for (int off = 32; off >= 1; off >>= 1) part += __shfl_xor(part, off, 64);
    if ((tid & 63) == 0) red[tid >> 6] = part;
    __syncthreads();
    if (tid == 0) lgits[m] = red[0] + red[1] + red[2] + red[3] + Ob[0];
}

// ---------------------------------------------------------------------------
// MFMA bf16 GEMM: C(M x N) = A(M x K bf16) @ W(N x K bf16)^T + bias
// 128x128 tile, 256 thr (4 waves, 2x2 of 64x64), BK=32, 16x16x32 MFMA.
// Chunk-roll swizzle keeps fragment ds_read_b128 2-way (free).
// Epilogue: separate et[4][32][72] stage, two passes (35 KB LDS total).
// NOTE: do NOT shrink LDS below this — 5 blocks/CU thrashes per-XCD L2 on
// the A rows (r10: FETCH +18 MB, L1 gemm 77->91 us). 4 blocks/CU is optimal.
// MODE 1: row-major bf16 store (RELU optional)
// MODE 3: relu, dot with OW, atomicAdd into lg[row] (no store)
// MODE 4: V^T scatter [bh][d][t]; A rows consumed in (b,t)-permuted order
// MODE 5: merged Q|K scatter [bh][t][d]; cols<512 -> Cb (scaled 1/8, bias),
//         cols>=512 -> Cb2 (bias2)
// ---------------------------------------------------------------------------
template<int MODE, bool RELU>
__global__ __launch_bounds__(256) void mgemm(
    const ushort_t* __restrict__ A, int lda,
    const ushort_t* __restrict__ W, int ldw,
    const float* __restrict__ bias, const float* __restrict__ bias2,
    ushort_t* __restrict__ Cb, ushort_t* __restrict__ Cb2, int ldc, int K,
    const float* __restrict__ OW, float* __restrict__ lg)
{
    __shared__ __align__(16) ushort_t As[128 * 32];
    __shared__ __align__(16) ushort_t Ws[128 * 32];
    __shared__ __align__(16) ushort_t et[4][32][72];   // epilogue stage (half)

    const int m0 = blockIdx.x * 128;
    const int n0 = blockIdx.y * 128;
    const int tid  = threadIdx.x;
    const int wave = tid >> 6;
    const int lane = tid & 63;
    const int wm = wave & 1, wn = wave >> 1;

    f32x4 acc[4][4] = {};

    const int srow = lane >> 2;
    // swizzle: physical LDS chunk = lane&3 (DMA-fixed); global source chunk
    // rolled by (row>>1)&3 so fragment reads spread 2-way across banks.
    const int lchunk = ((((lane & 3) - ((srow >> 1) & 3)) & 3)) * 8;
    int arowA, arowB;
    if (MODE == 4) {
        int mA = m0 + wave * 32 + srow;        // output m = b*512 + t
        int mB = mA + 16;
        arowA = ((mA & 511) << 5) + (mA >> 9); // actual token row t*32+b
        arowB = ((mB & 511) << 5) + (mB >> 9);
    } else {
        arowA = m0 + wave * 32 + srow;
        arowB = arowA + 16;
    }
    const ushort_t* Ag0 = A + (size_t)arowA * lda + lchunk;
    const ushort_t* Ag1 = A + (size_t)arowB * lda + lchunk;
    const ushort_t* Wg0 = W + (size_t)(n0 + wave * 32 + srow) * ldw + lchunk;
    const ushort_t* Wg1 = Wg0 + (size_t)16 * ldw;
    ushort_t* Al0 = &As[(wave * 32) * 32];
    ushort_t* Al1 = &As[(wave * 32 + 16) * 32];
    ushort_t* Wl0 = &Ws[(wave * 32) * 32];
    ushort_t* Wl1 = &Ws[(wave * 32 + 16) * 32];

    const int fr   = lane & 15;      // fragment row(A)/col(B)
    const int quad = lane >> 4;
    // fragment phys chunk: (quad + (row>>1)) & 3; row ≡ fr (mod 8) here
    const int csw  = ((quad + ((fr >> 1) & 3)) & 3) * 8;

    for (int k0 = 0; k0 < K; k0 += 32) {
        gload_lds16(Ag0 + k0, Al0);
        gload_lds16(Ag1 + k0, Al1);
        gload_lds16(Wg0 + k0, Wl0);
        gload_lds16(Wg1 + k0, Wl1);
        __syncthreads();
        short8 af[4], wf[4];
#pragma unroll
        for (int i = 0; i < 4; i++)
            af[i] = *(const short8*)&As[(wm * 64 + i * 16 + fr) * 32 + csw];
#pragma unroll
        for (int j = 0; j < 4; j++)
            wf[j] = *(const short8*)&Ws[(wn * 64 + j * 16 + fr) * 32 + csw];
#pragma unroll
        for (int i = 0; i < 4; i++)
#pragma unroll
            for (int j = 0; j < 4; j++)
                acc[i][j] = __builtin_amdgcn_mfma_f32_16x16x32_bf16(
                    af[i], wf[j], acc[i][j], 0, 0, 0);
        __syncthreads();
    }

    // C/D layout: col = lane&15, row = quad*4 + reg (per 16x16 frag)
    if (MODE == 3) {
#pragma unroll
        for (int i = 0; i < 4; i++)
#pragma unroll
            for (int r = 0; r < 4; r++) {
                int row = m0 + wm * 64 + i * 16 + quad * 4 + r;
                float part = 0.f;
#pragma unroll
                for (int j = 0; j < 4; j++) {
                    int col = n0 + wn * 64 + j * 16 + fr;
                    float v = fmaxf(acc[i][j][r] + bias[col], 0.f);
                    part = fmaf(v, OW[col], part);
                }
                part += __shfl_xor(part, 1, 64);
                part += __shfl_xor(part, 2, 64);
                part += __shfl_xor(part, 4, 64);
                part += __shfl_xor(part, 8, 64);
                if (fr == 0) atomicAdd(&lg[row], part);
            }
        return;
    }

    const int nbase = n0 + wn * 64;
    bool side = (MODE == 5) && (nbase >= 512);
    const float* bp = side ? bias2 : bias;
    const int boff  = (MODE == 5) ? (nbase & 511) : nbase;
    const float scl = (MODE == 5 && !side) ? 0.125f : 1.f;

    const int sub8 = (lane & 7) * 8;
    const int grp  = lane >> 3;                      // 0..7

#pragma unroll
    for (int hh = 0; hh < 2; hh++) {
        // ---- stage half (wave-private, LDS ops in-order per wave) ----
        if (MODE == 4) {
            // halve over columns cl (output d): j in {2hh, 2hh+1}
#pragma unroll
            for (int i = 0; i < 4; i++)
#pragma unroll
                for (int r = 0; r < 4; r++) {
                    int rl = i * 16 + quad * 4 + r;
#pragma unroll
                    for (int j = 2 * hh; j < 2 * hh + 2; j++) {
                        int cl = j * 16 + fr;
                        float v = acc[i][j][r] + bp[boff + cl];
                        if (RELU) v = fmaxf(v, 0.f);
                        et[wave][cl - 32 * hh][rl] = f2bf(v);
                    }
                }
        } else {
            // halve over rows rl: i in {2hh, 2hh+1}
#pragma unroll
            for (int i = 2 * hh; i < 2 * hh + 2; i++)
#pragma unroll
                for (int r = 0; r < 4; r++) {
                    int rl = i * 16 + quad * 4 + r;
#pragma unroll
                    for (int j = 0; j < 4; j++) {
                        int cl = j * 16 + fr;
                        float v = (acc[i][j][r] + bp[boff + cl]) * scl;
                        if (RELU) v = fmaxf(v, 0.f);
                        et[wave][rl - 32 * hh][cl] = f2bf(v);
                    }
                }
        }
        // ---- coalesced readback + store: 32 rows x 64 cols ----
#pragma unroll
        for (int rr = 0; rr < 4; rr++) {
            int rowl = rr * 8 + grp;                 // 0..31
            short8 val = *(const short8*)&et[wave][rowl][sub8];
            if (MODE == 1) {
                int row = m0 + wm * 64 + 32 * hh + rowl;
                int col = nbase + sub8;
                *(short8*)&Cb[(size_t)row * ldc + col] = val;
            } else if (MODE == 5) {
                int row = m0 + wm * 64 + 32 * hh + rowl;   // t*32 + b
                int t = row >> 5, b = row & 31;
                int h = (nbase >> 6) & 7;
                ushort_t* base = side ? Cb2 : Cb;
                *(short8*)&base[(((size_t)(b * 8 + h)) << 15) + ((size_t)t << 6) + sub8] = val;
            } else { // MODE 4
                int m = m0 + wm * 64 + sub8;         // 8 consecutive t, same b
                int b = m >> 9, t = m & 511;
                int h = nbase >> 6;
                int d = 32 * hh + rowl;
                *(short8*)&Cb[(((size_t)(b * 8 + h)) << 15) + ((size_t)d << 9) + t] = val;
            }
        }
    }
}

// ---------------------------------------------------------------------------
// MFMA flash attention, no-rescale softmax, cooperative async K/V LDS staging
// (m97-style: prefetch tile i+1 after the loop-top barrier, in flight during
// tile i's compute). XOR-chunk swizzle (phys chunk = (logical+row)&7, applied
// on the per-lane GLOBAL source address) keeps ds_read_b128 bank-uniform.
// grid=(B*NH, 8 rev q-tiles), 256thr. qb pre-scaled 1/8.
// kb: bf16 [bh][t][64]; vtb: bf16 [bh][d][512].
// ---------------------------------------------------------------------------
__global__ __launch_bounds__(256) void attn_mfma(
    const ushort_t* __restrict__ qb, const ushort_t* __restrict__ kb,
    const ushort_t* __restrict__ vtb, const float* __restrict__ mask,
    const float* __restrict__ gammas, ushort_t* __restrict__ attnc)
{
    __shared__ __align__(16) ushort_t kbuf[2][64 * 64];  // 16 KB
    __shared__ __align__(16) ushort_t vbuf[2][64 * 64];  // 16 KB
    __shared__ __align__(16) ushort_t ps[4][16][72];     // P / O stage, per wave
    __shared__ float decayF[512];
    __shared__ float mneg[512];

    const int bh  = blockIdx.x;          // b*8 + h
    const int b   = bh >> 3;
    const int h   = bh & 7;
    const int qt0 = (7 - blockIdx.y) * 64;   // heavy tiles first
    const int tid  = threadIdx.x;
    const int wave = tid >> 6;
    const int lane = tid & 63;
    const int fr   = lane & 15;
    const int quad = lane >> 4;

    {   // LUTs: decay' = clip(exp(-sp*sqrt(d)),1e-5,..)*log2e ; mneg = 0/-1e32
        float g  = gammas[h];
        float sp = (g > 20.f) ? g : log1pf(expf(g));
        for (int i = tid; i < 512; i += 256) {
            decayF[i] = fmaxf(exp2f(-sp * 1.44269504f * sqrtf((float)i)), 1e-5f)
                        * 1.44269504f;
            mneg[i]   = (mask[(size_t)i * B_SZ + b] == 0.f) ? -1e32f : 0.f;
        }
        // visibility covered by the loop-top __syncthreads below
    }

    const int qr0 = qt0 + wave * 16;
    const ushort_t* qbase = qb  + ((size_t)bh << 15);   // [t][64]
    const ushort_t* kbase = kb  + ((size_t)bh << 15);
    const ushort_t* vbase = vtb + ((size_t)bh << 15);   // [d][512]

    short8 af0 = *(const short8*)(qbase + (size_t)(qr0 + fr) * 64 + quad * 8);
    short8 af1 = *(const short8*)(qbase + (size_t)(qr0 + fr) * 64 + 32 + quad * 8);
    const short8 ones = {0x3F80, 0x3F80, 0x3F80, 0x3F80,
                         0x3F80, 0x3F80, 0x3F80, 0x3F80};

    // staging: wave stages local rows [wave*16, wave*16+16) of K and V tiles.
    // lane L covers local row rl = wave*16 + (L>>3), physical chunk L&7;
    // global source chunk = ((L&7) - rl) & 7  (XOR-roll swizzle).
    const int rl0 = wave * 16 + (lane >> 3);
    const int rl1 = rl0 + 8;
    const int sc0 = (((lane & 7) - rl0) & 7) * 8;   // ushort offset
    const int sc1 = (((lane & 7) - rl1) & 7) * 8;

    auto stage = [&](int kt, int bufi) {
        gload_lds16(kbase + (size_t)(kt + rl0) * 64 + sc0, &kbuf[bufi][(wave * 16) * 64]);
        gload_lds16(kbase + (size_t)(kt + rl1) * 64 + sc1, &kbuf[bufi][(wave * 16 + 8) * 64]);
        gload_lds16(vbase + (size_t)rl0 * T_LEN + kt + sc0, &vbuf[bufi][(wave * 16) * 64]);
        gload_lds16(vbase + (size_t)rl1 * T_LEN + kt + sc1, &vbuf[bufi][(wave * 16 + 8) * 64]);
    };
    auto frag = [&](const ushort_t* buf, int row, int lchunk) -> short8 {
        return *(const short8*)&buf[row * 64 + ((lchunk + row) & 7) * 8];
    };

    stage(0, 0);

    f32x4 o[4] = {};                    // O[q=quad*4+r][d=j2*16+fr]
    f32x4 lacc = {};                    // row sums, same layout rows
    int bufi = 0;

    for (int kt0 = 0; kt0 <= qt0; kt0 += 64) {
        __syncthreads();                // drains staged loads; buffer handoff
        if (kt0 < qt0) stage(kt0 + 64, bufi ^ 1);   // prefetch during compute
        const bool diag = (kt0 == qt0);
        const ushort_t* kb_ = kbuf[bufi];
        const ushort_t* vb_ = vbuf[bufi];

        // ---- S = Q K^T (16 x 64) ----
        f32x4 sacc[4] = {};
#pragma unroll
        for (int j = 0; j < 4; j++) {
            int row = j * 16 + fr;
            short8 k0 = frag(kb_, row, quad);
            short8 k1 = frag(kb_, row, quad + 4);
            sacc[j] = __builtin_amdgcn_mfma_f32_16x16x32_bf16(af0, k0, sacc[j], 0, 0, 0);
            sacc[j] = __builtin_amdgcn_mfma_f32_16x16x32_bf16(af1, k1, sacc[j], 0, 0, 0);
        }

        // ---- softmax (no rescale): p = exp2(fma(s, decay', mneg)) ----
#pragma unroll
        for (int j = 0; j < 4; j++) {
            int kg = kt0 + j * 16 + fr;
            float mn = mneg[kg];
            int qgb = qr0 + quad * 4;
            if (!diag) {
                int base = qgb - kg;
#pragma unroll
                for (int r = 0; r < 4; r++) {
                    float t = fmaf(sacc[j][r], decayF[base + r], mn);
                    union { float f; unsigned u; } cv; cv.f = exp2f(t);
                    ps[wave][quad * 4 + r][j * 16 + fr] = (ushort_t)(cv.u >> 16);
                }
            } else {
#pragma unroll
                for (int r = 0; r < 4; r++) {
                    int didx = qgb + r - kg;
                    float dec = decayF[didx > 0 ? didx : 0];
                    float t = fmaf(sacc[j][r], dec, mn);
                    if (didx <= 0) t = -1e32f;      // causal (kg >= qg)
                    union { float f; unsigned u; } cv; cv.f = exp2f(t);
                    ps[wave][quad * 4 + r][j * 16 + fr] = (ushort_t)(cv.u >> 16);
                }
            }
        }
        short8 pf0 = *(const short8*)&ps[wave][fr][quad * 8];
        short8 pf1 = *(const short8*)&ps[wave][fr][32 + quad * 8];
        lacc = __builtin_amdgcn_mfma_f32_16x16x32_bf16(pf0, ones, lacc, 0, 0, 0);
        lacc = __builtin_amdgcn_mfma_f32_16x16x32_bf16(pf1, ones, lacc, 0, 0, 0);
#pragma unroll
        for (int j2 = 0; j2 < 4; j2++) {
            int row = j2 * 16 + fr;
            short8 v0 = frag(vb_, row, quad);
            short8 v1 = frag(vb_, row, quad + 4);
            o[j2] = __builtin_amdgcn_mfma_f32_16x16x32_bf16(pf0, v0, o[j2], 0, 0, 0);
            o[j2] = __builtin_amdgcn_mfma_f32_16x16x32_bf16(pf1, v1, o[j2], 0, 0, 0);
        }
        bufi ^= 1;
    }

    // epilogue: divide by l, zero row q==0, stage + coalesced store
#pragma unroll
    for (int r = 0; r < 4; r++) {
        int qg = qr0 + quad * 4 + r;
        float linv = (qg == 0) ? 0.f : 1.f / lacc[r];
#pragma unroll
        for (int j2 = 0; j2 < 4; j2++)
            ps[wave][quad * 4 + r][j2 * 16 + fr] = f2bf(o[j2][r] * linv);
    }
    const int sub8 = (lane & 7) * 8;
    const int grp  = lane >> 3;
#pragma unroll
    for (int half = 0; half < 2; half++) {
        int rowl = half * 8 + grp;                   // 0..15
        short8 val = *(const short8*)&ps[wave][rowl][sub8];
        int qg = qr0 + rowl;
        *(short8*)&attnc[((size_t)qg * B_SZ + b) * H_DIM + h * DHEAD + sub8] = val;
    }
}

// ---------------------------------------------------------------------------
// LN1: reads bf16 X, writes bf16 out1 only (residual kept in bf16)
// ---------------------------------------------------------------------------
__global__ __launch_bounds__(256) void ln1_kernel(
    const ushort_t* __restrict__ X, const float* __restrict__ g,
    const float* __restrict__ bta, ushort_t* __restrict__ Yb)
{
    int m    = blockIdx.x * 4 + (threadIdx.x >> 6);
    int lane = threadIdx.x & 63;
    int c0   = lane * 8;
    const ushort_t* xr = X + (size_t)m * H_DIM + c0;
    float x[8];
    float s = 0.f, ss = 0.f;
    short8 xv = *(const short8*)xr;
#pragma unroll
    for (int i = 0; i < 8; i++) {
        x[i] = bf2f((ushort_t)xv[i]);
        s += x[i]; ss += x[i] * x[i];
    }
#pragma unroll
    for (int off = 32; off >= 1; off >>= 1) {
        s  += __shfl_xor(s,  off, 64);
        ss += __shfl_xor(ss, off, 64);
    }
    float mu  = s * (1.f / 512.f);
    float var = ss * (1.f / 512.f) - mu * mu;
    float rs  = rsqrtf(var + 1e-5f);
    ushort_t yb[8];
#pragma unroll
    for (int i = 0; i < 8; i++)
        yb[i] = f2bf((x[i] - mu) * rs * g[c0 + i] + bta[c0 + i]);
    *(short8*)(Yb + (size_t)m * H_DIM + c0) = *(short8*)&yb[0];
}

// ---------------------------------------------------------------------------
// LN2 + residual (bf16) + fused OW-dot: pred_bf[:,0:512] = bf16(res + LN(f2));
// lgits[m] += dot(row values, OW[0:512])
// ---------------------------------------------------------------------------
__global__ __launch_bounds__(256) void ln2_kernel(
    const ushort_t* __restrict__ X, const float* __restrict__ g,
    const float* __restrict__ bta, const ushort_t* __restrict__ res,
    ushort_t* __restrict__ pred_bf, const float* __restrict__ OW,
    float* __restrict__ lg)
{
    int m    = blockIdx.x * 4 + (threadIdx.x >> 6);
    int lane = threadIdx.x & 63;
    int c0   = lane * 8;
    const ushort_t* xr = X + (size_t)m * H_DIM + c0;
    float x[8];
    float s = 0.f, ss = 0.f;
    short8 xv = *(const short8*)xr;
#pragma unroll
    for (int i = 0; i < 8; i++) {
        x[i] = bf2f((ushort_t)xv[i]);
        s += x[i]; ss += x[i] * x[i];
    }
#pragma unroll
    for (int off = 32; off >= 1; off >>= 1) {
        s  += __shfl_xor(s,  off, 64);
        ss += __shfl_xor(ss, off, 64);
    }
    float mu  = s * (1.f / 512.f);
    float var = ss * (1.f / 512.f) - mu * mu;
    float rs  = rsqrtf(var + 1e-5f);
    short8 rv = *(const short8*)(res + (size_t)m * H_DIM + c0);
    ushort_t yb[8];
    float part = 0.f;
#pragma unroll
    for (int i = 0; i < 8; i++) {
        float v = (x[i] - mu) * rs * g[c0 + i] + bta[c0 + i] + bf2f((ushort_t)rv[i]);
        yb[i] = f2bf(v);
        part = fmaf(v, OW[c0 + i], part);
    }
    *(short8*)(pred_bf + (size_t)m * P_DIM + c0) = *(short8*)&yb[0];
#pragma unroll
    for (int off = 32; off >= 1; off >>= 1) part += __shfl_xor(part, off, 64);
    if (lane == 0) lg[m] += part;
}

// ---------------------------------------------------------------------------
__global__ __launch_bounds__(256) void bce_kernel(
    const float* __restrict__ lg, const int* __restrict__ labels,
    const float* __restrict__ mask, float* __restrict__ accum)
{
    int m    = blockIdx.x * 256 + threadIdx.x;
    int lane = threadIdx.x & 63;
    float l  = lg[m];
    float y  = (float)labels[m];
    float mv = mask[m];
    float a  = (fmaxf(l, 0.f) - l * y + log1pf(expf(-fabsf(l)))) * mv;
#pragma unroll
    for (int off = 32; off >= 1; off >>= 1) {
        a  += __shfl_xor(a,  off, 64);
        mv += __shfl_xor(mv, off, 64);
    }
    if (lane == 0) {
        atomicAdd(accum,     a);
        atomicAdd(accum + 1, mv);
    }
}

__global__ void finalize_kernel(const float* __restrict__ accum, float* __restrict__ out)
{
    out[0] = accum[0] / accum[1];
}

// ---------------------------------------------------------------------------
extern "C" void kernel_launch(void* const* d_in, const int* in_sizes, int n_in,
                              void* d_out, int out_size, void* d_ws, size_t ws_size,
                              hipStream_t stream)
{
    (void)in_sizes; (void)n_in; (void)out_size;
    const int*   ans    = (const int*)  d_in[0];
    const int*   cans   = (const int*)  d_in[1];
    const int*   labels = (const int*)  d_in[2];
    const float* mask   = (const float*)d_in[3];
    const int*   qids   = (const int*)  d_in[4];
    const int*   sids   = (const int*)  d_in[5];
    const float* smask  = (const float*)d_in[6];
    const float* Eq     = (const float*)d_in[7];
    const float* Es     = (const float*)d_in[8];
    const float* Ea     = (const float*)d_in[9];
    const float* El     = (const float*)d_in[10];
    const float* Wq     = (const float*)d_in[11];
    const float* bq     = (const float*)d_in[12];
    const float* Wk     = (const float*)d_in[13];
    const float* bk     = (const float*)d_in[14];
    const float* Wv     = (const float*)d_in[15];
    const float* bv     = (const float*)d_in[16];
    const float* Wo     = (const float*)d_in[17];
    const float* bo     = (const float*)d_in[18];
    const float* ln1_g  = (const float*)d_in[19];
    const float* ln1_b  = (const float*)d_in[20];
    const float* W1     = (const float*)d_in[21];
    const float* b1     = (const float*)d_in[22];
    const float* W2     = (const float*)d_in[23];
    const float* b2     = (const float*)d_in[24];
    const float* ln2_g  = (const float*)d_in[25];
    const float* ln2_b  = (const float*)d_in[26];
    const float* gammas = (const float*)d_in[27];
    const float* L1W    = (const float*)d_in[28];
    const float* L1b    = (const float*)d_in[29];
    const float* L2W    = (const float*)d_in[30];
    const float* L2b    = (const float*)d_in[31];
    const float* OW     = (const float*)d_in[32];
    const float* Ob     = (const float*)d_in[33];
    float* out = (float*)d_out;

    // Arena in units U = TB*64 floats (4 MiB). Peak 42U ≈ 176 MB.
    const size_t U = (size_t)TBTOK * 64;
    if (ws_size < 42 * U * sizeof(float)) return;
    float* ws = (float*)d_ws;
    ushort_t* wtb      = (ushort_t*)(ws);            // [0,3)  weights bf16 (perm)
    ushort_t* pred_bf  = (ushort_t*)(ws + 3 * U);    // [3,12) perm
    ushort_t* value_bf = (ushort_t*)(ws + 12 * U);   // [12,21) until V-gemm
    ushort_t* qb       = (ushort_t*)(ws + 21 * U);   // [21,25) until attn
    ushort_t* kb       = (ushort_t*)(ws + 25 * U);   // [25,29) until attn
    ushort_t* vtb      = (ushort_t*)(ws + 29 * U);   // [29,33) until attn
    ushort_t* attnc_bf = (ushort_t*)(ws + 33 * U);   // [33,37) until Wo
    ushort_t* x1_bf    = (ushort_t*)(ws + 12 * U);   // [12,16) Wo-out / LN1-in
    ushort_t* out1_bf  = (ushort_t*)(ws + 24 * U);   // [24,28) LN1..LN2 (bf16)
    ushort_t* f1_bf    = (ushort_t*)(ws + 28 * U);   // [28,32) W1-out
    ushort_t* f2_bf    = (ushort_t*)(ws + 32 * U);   // [32,36) W2-out / LN2-in
    ushort_t* h1_bf    = (ushort_t*)(ws + 12 * U);   // [12,21) L1-out
    float*    lgits    = ws + 41 * U;                // TB floats
    float*    accum    = lgits + TBTOK;

    // bf16 weight arena offsets (elements); wq||wk contiguous for merged QK
    ushort_t* wqk_b = wtb + 0;         // 1024 x 640
    ushort_t* wv_b  = wtb + 655360;
    ushort_t* wo_b  = wtb + 1245184;
    ushort_t* w1_b  = wtb + 1507328;
    ushort_t* w2_b  = wtb + 1769472;
    ushort_t* l1_b  = wtb + 2031616;
    ushort_t* l2_b  = wtb + 3358720;

    convert_weights<<<4576, 256, 0, stream>>>(Wq, Wk, Wv, Wo, W1, W2, L1W, L2W,
                                              wtb, accum);
    // embeddings + fused logits tail dot
    embed_kernel<<<TBTOK, 256, 0, stream>>>(ans, cans, labels, mask, qids, sids,
                                            smask, Eq, Es, Ea, El, pred_bf, value_bf,
                                            OW, Ob, lgits);
    // merged Q|K projection (Q pre-scaled by 1/8), then V^T
    mgemm<5,false><<<dim3(TBTOK/128, 8), 256, 0, stream>>>(
        pred_bf + 512, P_DIM, wqk_b, 640, bq, bk, qb, kb, 0, 640, nullptr, nullptr);
    mgemm<4,false><<<dim3(TBTOK/128, 4), 256, 0, stream>>>(
        value_bf, P_DIM, wv_b, P_DIM, bv, nullptr, vtb, nullptr, 0, P_DIM, nullptr, nullptr);
    // attention (MFMA flash, async LDS staging)
    attn_mfma<<<dim3(B_SZ * NHEAD, 8), 256, 0, stream>>>(
        qb, kb, vtb, mask, gammas, attnc_bf);
    // output projection -> x1_bf
    mgemm<1,false><<<dim3(TBTOK/128, 4), 256, 0, stream>>>(
        attnc_bf, H_DIM, wo_b, H_DIM, bo, nullptr, x1_bf, nullptr, H_DIM, H_DIM, nullptr, nullptr);
    ln1_kernel<<<TBTOK/4, 256, 0, stream>>>(x1_bf, ln1_g, ln1_b, out1_bf);
    // FFN
    mgemm<1,true><<<dim3(TBTOK/128, 4), 256, 0, stream>>>(
        out1_bf, H_DIM, w1_b, H_DIM, b1, nullptr, f1_bf, nullptr, H_DIM, H_DIM, nullptr, nullptr);
    mgemm<1,false><<<dim3(TBTOK/128, 4), 256, 0, stream>>>(
        f1_bf, H_DIM, w2_b, H_DIM, b2, nullptr, f2_bf, nullptr, H_DIM, H_DIM, nullptr, nullptr);
    // LN2 + bf16 residual + fused head-dot into lgits
    ln2_kernel<<<TBTOK/4, 256, 0, stream>>>(f2_bf, ln2_g, ln2_b, out1_bf, pred_bf, OW, lgits);
    // L1 (relu)
    mgemm<1,true><<<dim3(TBTOK/128, 9), 256, 0, stream>>>(
        pred_bf, P_DIM, l1_b, P_DIM, L1b, nullptr, h1_bf, nullptr, P_DIM, P_DIM, nullptr, nullptr);
    // L2 (relu) fused with OW dot -> atomics into lgits
    mgemm<3,true><<<dim3(TBTOK/128, 9), 256, 0, stream>>>(
        h1_bf, P_DIM, l2_b, P_DIM, L2b, nullptr, nullptr, nullptr, 0, P_DIM, OW, lgits);
    // BCE + reduction
    bce_kernel<<<TBTOK/256, 256, 0, stream>>>(lgits, labels, mask, accum);
    finalize_kernel<<<1, 1, 0, stream>>>(accum, out);
}